// Round 7
// baseline (1030.447 us; speedup 1.0000x reference)
//
#include <hip/hip_runtime.h>
#include <hip/hip_bf16.h>
#include <math.h>

typedef __hip_bfloat16 bf16;
typedef __bf16 bf16x8 __attribute__((ext_vector_type(8)));
typedef float f32x4 __attribute__((ext_vector_type(4)));

#define NDEPTH 4
#define DIM 768
#define HEADS 12
#define DH 64
#define INNER 768
#define FFI 2048
#define BB 4
#define NN 1024
#define ROWS (BB*NN)   // 4096

__device__ __forceinline__ void async_cp16(const bf16* g, bf16* l) {
  __builtin_amdgcn_global_load_lds(
      (const __attribute__((address_space(1))) unsigned int*)g,
      (__attribute__((address_space(3))) unsigned int*)l, 16, 0, 0);
}

// ---------------------------------------------------------------------------
// bf16 MFMA GEMM body. C = A @ Bt^T. K, LD compile-time; K-loop fully
// unrolled; 128xBN tile, BK=64, 4 waves, XOR-swizzled LDS.
// EP=0: plain (Cb/Cf/Rf).
// EP=1: FF1 LN-fold + SwiGLU: u = rstd*(acc - mu*va[col]) + vb[col]; N is
//       interleaved (a,g); writes a*gelu(g) to Cb, N/2 cols.
// EP=2: QKV. cols [0,768): q = acc - mu*va[col] -> Cb (rstd dropped: rope's
//       l2norm cancels row-uniform scale). [768,1536): k -> aux1 compact.
//       [1536,2304): v -> aux2 transposed (b,h,dh,n), packed 8B.
// ---------------------------------------------------------------------------
template<int BN, int EP, int K, int LD>
__device__ __forceinline__ void gemm_body(
    const bf16* __restrict__ A, const bf16* __restrict__ Bt,
    bf16* __restrict__ Cb, float* __restrict__ Cf, const float* __restrict__ Rf,
    const float2* __restrict__ musig, const float* __restrict__ va,
    const float* __restrict__ vb, bf16* __restrict__ aux1, bf16* __restrict__ aux2,
    int M, int N, int bx, int by, bf16* As, bf16* Bs)
{
  constexpr int WN = BN / 2;      // wave col extent
  constexpr int NT = WN / 16;     // col MFMA tiles per wave
  const int tid  = threadIdx.x;
  const int lane = tid & 63, w = tid >> 6;
  const int quad = lane >> 4, l16 = lane & 15;
  const int wr = w >> 1, wc = w & 1;
  const int m0 = by * 128, n0 = bx * BN;

  f32x4 acc[4][NT] = {};

  constexpr int CHA = 128 * 8;    // A chunks (8 x 16B per 64-elem row)
  constexpr int CH  = CHA + BN * 8;
  constexpr int NCH = CH / 256;

  #pragma unroll
  for (int kk = 0; kk < K; kk += 64) {
    __syncthreads();
    #pragma unroll
    for (int t = 0; t < NCH; ++t) {
      int c0 = w*64 + t*256;      // wave-uniform LDS base chunk
      int ch = c0 + lane;
      if (c0 < CHA) {
        int r = ch >> 3, j = (ch & 7) ^ (r & 7);
        async_cp16(&A[(size_t)(m0 + r)*LD + kk + j*8], &As[(size_t)c0*8]);
      } else {
        int ch2 = ch - CHA, r = ch2 >> 3, j = (ch2 & 7) ^ (r & 7);
        async_cp16(&Bt[(size_t)(n0 + r)*LD + kk + j*8], &Bs[(size_t)(c0 - CHA)*8]);
      }
    }
    __syncthreads();

    #pragma unroll
    for (int kc = 0; kc < 2; ++kc) {
      bf16x8 bfr[NT];
      #pragma unroll
      for (int nt = 0; nt < NT; ++nt) {
        int rb = wc*WN + nt*16 + l16;
        int c  = (kc*4 + quad) ^ (rb & 7);
        bfr[nt] = *(const bf16x8*)&Bs[rb*64 + c*8];
      }
      #pragma unroll
      for (int mt = 0; mt < 4; ++mt) {
        int ra = wr*64 + mt*16 + l16;
        int ca = (kc*4 + quad) ^ (ra & 7);
        bf16x8 af = *(const bf16x8*)&As[ra*64 + ca*8];
        #pragma unroll
        for (int nt = 0; nt < NT; ++nt)
          acc[mt][nt] = __builtin_amdgcn_mfma_f32_16x16x32_bf16(af, bfr[nt], acc[mt][nt], 0, 0, 0);
      }
    }
  }

  #pragma unroll
  for (int mt = 0; mt < 4; ++mt) {
    int row = m0 + wr*64 + mt*16 + quad*4;
    if (EP == 1) {
      float2 ms[4];
      #pragma unroll
      for (int r = 0; r < 4; ++r) ms[r] = musig[row + r];
      #pragma unroll
      for (int nt = 0; nt < NT; ++nt) {
        int col = n0 + wc*WN + nt*16 + l16;
        float vf = va[col], bf_ = vb[col];
        #pragma unroll
        for (int r = 0; r < 4; ++r) {
          float u = ms[r].y * (acc[mt][nt][r] - ms[r].x * vf) + bf_;
          float g = __shfl_xor(u, 1);            // even lane: u=a, g from odd
          if (!(lane & 1)) {
            float ge = 0.5f * g * (1.f + erff(g * 0.70710678118654752f));
            Cb[(size_t)(row + r)*(N >> 1) + (col >> 1)] = __float2bfloat16(u * ge);
          }
        }
      }
    } else if (EP == 2) {
      if (n0 < INNER) {                          // q region (block-uniform)
        float mu[4];
        #pragma unroll
        for (int r = 0; r < 4; ++r) mu[r] = musig[row + r].x;
        #pragma unroll
        for (int nt = 0; nt < NT; ++nt) {
          int col = n0 + wc*WN + nt*16 + l16;
          float vqc = va[col];
          #pragma unroll
          for (int r = 0; r < 4; ++r)
            Cb[(size_t)(row + r)*INNER + col] =
                __float2bfloat16(acc[mt][nt][r] - mu[r]*vqc);
        }
      } else if (n0 < 2*INNER) {                 // k region
        #pragma unroll
        for (int nt = 0; nt < NT; ++nt) {
          int col = n0 + wc*WN + nt*16 + l16;
          #pragma unroll
          for (int r = 0; r < 4; ++r)
            aux1[(size_t)(row + r)*INNER + (col - INNER)] =
                __float2bfloat16(acc[mt][nt][r]);
        }
      } else {                                   // v region -> (b,h,dh,n)
        #pragma unroll
        for (int nt = 0; nt < NT; ++nt) {
          int col = n0 + wc*WN + nt*16 + l16;
          int c2 = col - 2*INNER, hh = c2 >> 6, d = c2 & 63;
          int b = row >> 10, nn = row & 1023;
          union { ushort4 u4; bf16 h4[4]; } p;
          #pragma unroll
          for (int r = 0; r < 4; ++r) p.h4[r] = __float2bfloat16(acc[mt][nt][r]);
          *(ushort4*)&aux2[(((size_t)b*HEADS + hh)*DH + d)*NN + nn] = p.u4;
        }
      }
    } else {
      #pragma unroll
      for (int nt = 0; nt < NT; ++nt) {
        int col = n0 + wc*WN + nt*16 + l16;
        #pragma unroll
        for (int r = 0; r < 4; ++r) {
          float v = acc[mt][nt][r];
          size_t idx = (size_t)(row + r) * N + col;
          if (Rf) v += Rf[idx];
          if (Cf) Cf[idx] = v;
          if (Cb) Cb[idx] = __float2bfloat16(v);
        }
      }
    }
  }
}

// FF1: LN-fold + SwiGLU fused
__global__ __launch_bounds__(256) void ff1_kernel(
    const bf16* __restrict__ A, const bf16* __restrict__ Bt,
    bf16* __restrict__ Cb, const float2* __restrict__ musig,
    const float* __restrict__ va, const float* __restrict__ vb, int M, int N)
{
  __shared__ __align__(16) bf16 As[128*64];
  __shared__ __align__(16) bf16 Bs[128*64];
  gemm_body<128,1,768,768>(A, Bt, Cb, nullptr, nullptr, musig, va, vb,
                           nullptr, nullptr, M, N, blockIdx.x, blockIdx.y, As, Bs);
}

// QKV: one uniform GEMM, N=2304 (q-fold | k | v-transposed)
__global__ __launch_bounds__(256) void qkv_kernel(
    const bf16* __restrict__ x16, const bf16* __restrict__ Bt,
    bf16* __restrict__ qb, bf16* __restrict__ kb, bf16* __restrict__ vt,
    const float2* __restrict__ musig, const float* __restrict__ vqv)
{
  __shared__ __align__(16) bf16 As[128*64];
  __shared__ __align__(16) bf16 Bs[128*64];
  gemm_body<128,2,768,768>(x16, Bt, qb, nullptr, nullptr, musig, vqv, nullptr,
                           kb, vt, ROWS, 3*INNER, blockIdx.x, blockIdx.y, As, Bs);
}

// Split-K=2: z selects K-half; partials to P[z*M*N]
template<int BN, int KH, int LD>
__global__ __launch_bounds__(256) void gemm_splitk_kernel(
    const bf16* __restrict__ A, const bf16* __restrict__ Bt,
    float* __restrict__ P, int M, int N)
{
  __shared__ __align__(16) bf16 As[128*64];
  __shared__ __align__(16) bf16 Bs[BN*64];
  const int z = blockIdx.z;
  gemm_body<BN,0,KH,LD>(A + (size_t)z*KH, Bt + (size_t)z*KH, nullptr,
                        P + (size_t)z*M*N, nullptr, nullptr, nullptr, nullptr,
                        nullptr, nullptr, M, N, blockIdx.x, blockIdx.y, As, Bs);
}

// ---------------------------------------------------------------------------
// Row stats of f32 x (row=768): musig[row]={mu,rstd}; also bf16 shadow out.
// ---------------------------------------------------------------------------
__global__ __launch_bounds__(256) void stats_kernel(
    const float* __restrict__ x, bf16* __restrict__ xo16,
    float2* __restrict__ musig)
{
  const int row = blockIdx.x, tid = threadIdx.x;
  const size_t base = (size_t)row * DIM;
  float v[3];
  #pragma unroll
  for (int j = 0; j < 3; ++j) {
    v[j] = x[base + tid + j*256];
    xo16[base + tid + j*256] = __float2bfloat16(v[j]);
  }
  float s  = v[0] + v[1] + v[2];
  float ss = v[0]*v[0] + v[1]*v[1] + v[2]*v[2];
  #pragma unroll
  for (int off = 32; off; off >>= 1) { s += __shfl_xor(s, off); ss += __shfl_xor(ss, off); }
  __shared__ float red[8];
  int w = tid >> 6;
  if ((tid & 63) == 0) { red[w] = s; red[w + 4] = ss; }
  __syncthreads();
  s  = red[0] + red[1] + red[2] + red[3];
  ss = red[4] + red[5] + red[6] + red[7];
  float mean = s * (1.f/768.f);
  float var  = ss * (1.f/768.f) - mean*mean;
  float rstd = rsqrtf(fmaxf(var, 0.f) + 1e-5f);
  if (tid == 0) musig[row] = make_float2(mean, rstd);
}

// ---------------------------------------------------------------------------
// Split-K reduce + residual + stats (no LN output; LN folded into GEMMs)
// ---------------------------------------------------------------------------
__global__ __launch_bounds__(256) void redln_kernel(
    const float* __restrict__ P0, const float* __restrict__ P1,
    const float* __restrict__ res,
    float* __restrict__ xo32, bf16* __restrict__ xo16, float* __restrict__ outf,
    float2* __restrict__ musig)
{
  const int row = blockIdx.x, tid = threadIdx.x;
  const size_t base = (size_t)row * DIM;
  float v[3];
  #pragma unroll
  for (int j = 0; j < 3; ++j) {
    size_t idx = base + tid + j*256;
    v[j] = res[idx] + P0[idx] + P1[idx];
    if (xo32) xo32[idx] = v[j];
    if (xo16) xo16[idx] = __float2bfloat16(v[j]);
    if (outf) outf[idx] = v[j];
  }
  float s  = v[0] + v[1] + v[2];
  float ss = v[0]*v[0] + v[1]*v[1] + v[2]*v[2];
  #pragma unroll
  for (int off = 32; off; off >>= 1) { s += __shfl_xor(s, off); ss += __shfl_xor(ss, off); }
  __shared__ float red[8];
  int w = tid >> 6;
  if ((tid & 63) == 0) { red[w] = s; red[w + 4] = ss; }
  __syncthreads();
  s  = red[0] + red[1] + red[2] + red[3];
  ss = red[4] + red[5] + red[6] + red[7];
  float mean = s * (1.f/768.f);
  float var  = ss * (1.f/768.f) - mean*mean;
  float rstd = rsqrtf(fmaxf(var, 0.f) + 1e-5f);
  if (tid == 0) musig[row] = make_float2(mean, rstd);
}

// ---------------------------------------------------------------------------
// RoPE (2D, H=32) + L2-norm + per-dim scale; q gets ATTN_SCALE folded in.
// ---------------------------------------------------------------------------
__global__ __launch_bounds__(384) void rope_kernel(
    const bf16* __restrict__ q, const bf16* __restrict__ kb,
    const float* __restrict__ qsc, const float* __restrict__ ksc,
    bf16* __restrict__ qh, bf16* __restrict__ kh)
{
  const int bn = blockIdx.x;
  const int b = bn >> 10, n = bn & 1023;
  const int tid = threadIdx.x;
  const int h = tid >> 5, pr = tid & 31, d0 = pr*2;
  const float xp = (float)(n & 31), yp = (float)(n >> 5);
  const int t = pr >> 1;
  const float freq = powf(10000.f, -(float)t / 16.f);
  const float ang = (pr & 1) ? yp * freq : xp * freq;
  float sn, cs;
  sincosf(ang, &sn, &cs);
  const float2 qs2 = *(const float2*)&qsc[d0];
  const float2 ks2 = *(const float2*)&ksc[d0];

  union { unsigned int u; bf16 h2[2]; } qa, ka, qo, ko;
  qa.u = *(const unsigned int*)&q [(size_t)bn*INNER + h*64 + d0];
  ka.u = *(const unsigned int*)&kb[(size_t)bn*INNER + h*64 + d0];
  float qre = __bfloat162float(qa.h2[0]), qim = __bfloat162float(qa.h2[1]);
  float kre = __bfloat162float(ka.h2[0]), kim = __bfloat162float(ka.h2[1]);
  float qr = qre*cs - qim*sn, qi = qre*sn + qim*cs;
  float kr = kre*cs - kim*sn, ki = kre*sn + kim*cs;
  float q2 = qr*qr + qi*qi, k2 = kr*kr + ki*ki;
  #pragma unroll
  for (int off = 1; off < 32; off <<= 1) { q2 += __shfl_xor(q2, off); k2 += __shfl_xor(k2, off); }
  float qinv = 8.f / fmaxf(sqrtf(q2), 1e-12f);   // ATTN_SCALE folded into q
  float kinv = 1.f / fmaxf(sqrtf(k2), 1e-12f);
  qo.h2[0] = __float2bfloat16(qr * qinv * qs2.x);
  qo.h2[1] = __float2bfloat16(qi * qinv * qs2.y);
  ko.h2[0] = __float2bfloat16(kr * kinv * ks2.x);
  ko.h2[1] = __float2bfloat16(ki * kinv * ks2.y);
  size_t oi = (((size_t)b*HEADS + h)*NN + n)*DH + d0;
  *(unsigned int*)&qh[oi] = qo.u;
  *(unsigned int*)&kh[oi] = ko.u;
}

// ---------------------------------------------------------------------------
// Flash attention, fixed softmax max (Cauchy-Schwarz bound; 8 folded into q).
// ---------------------------------------------------------------------------
__global__ __launch_bounds__(256) void attn_kernel(
    const bf16* __restrict__ qh, const bf16* __restrict__ kh,
    const bf16* __restrict__ vt, const float* __restrict__ qsc,
    const float* __restrict__ ksc, bf16* __restrict__ ob)
{
  __shared__ __align__(16) bf16 Qs[64*72];
  __shared__ __align__(16) bf16 Ks[64*72];
  __shared__ __align__(16) bf16 Vt[64*72];
  __shared__ __align__(16) bf16 Ps[4][16*72];

  const int tid = threadIdx.x;
  const int lane = tid & 63, w = tid >> 6;
  const int quad = lane >> 4, l16 = lane & 15;
  const int qt = blockIdx.x, bh = blockIdx.y;
  const int b = bh / HEADS, h = bh % HEADS;
  const size_t base = (size_t)bh * NN * DH;

  float mq = fabsf(qsc[lane]), mk = fabsf(ksc[lane]);
  #pragma unroll
  for (int off = 1; off < 64; off <<= 1) {
    mq = fmaxf(mq, __shfl_xor(mq, off));
    mk = fmaxf(mk, __shfl_xor(mk, off));
  }
  const float Mb = 8.f * mq * mk;

  for (int c = tid; c < 512; c += 256) {
    int r = c >> 3, j = c & 7;
    *(uint4*)&Qs[r*72 + j*8] = *(const uint4*)&qh[base + (size_t)(qt*64 + r)*64 + j*8];
  }

  f32x4 o[4] = {};
  float pl[4] = {0.f, 0.f, 0.f, 0.f};

  for (int kt0 = 0; kt0 < NN/64; ++kt0) {
    __syncthreads();
    for (int c = tid; c < 512; c += 256) {
      int r = c >> 3, j = c & 7;
      *(uint4*)&Ks[r*72 + j*8] = *(const uint4*)&kh[base + (size_t)(kt0*64 + r)*64 + j*8];
      *(uint4*)&Vt[r*72 + j*8] = *(const uint4*)&vt[base + (size_t)r*NN + kt0*64 + j*8];
    }
    __syncthreads();

    f32x4 s[4] = {};
    bf16x8 aq[2];
    #pragma unroll
    for (int kc = 0; kc < 2; ++kc)
      aq[kc] = *(const bf16x8*)&Qs[(w*16 + l16)*72 + kc*32 + quad*8];
    #pragma unroll
    for (int kt = 0; kt < 4; ++kt)
      #pragma unroll
      for (int kc = 0; kc < 2; ++kc) {
        bf16x8 bk = *(const bf16x8*)&Ks[(kt*16 + l16)*72 + kc*32 + quad*8];
        s[kt] = __builtin_amdgcn_mfma_f32_16x16x32_bf16(aq[kc], bk, s[kt], 0, 0, 0);
      }

    #pragma unroll
    for (int r = 0; r < 4; ++r) {
      #pragma unroll
      for (int kt = 0; kt < 4; ++kt) {
        float pv = __expf(s[kt][r] - Mb);
        pl[r] += pv;
        Ps[w][(quad*4 + r)*72 + kt*16 + l16] = __float2bfloat16(pv);
      }
    }
    __syncthreads();

    #pragma unroll
    for (int kc = 0; kc < 2; ++kc) {
      bf16x8 ap = *(const bf16x8*)&Ps[w][l16*72 + kc*32 + quad*8];
      #pragma unroll
      for (int nt = 0; nt < 4; ++nt) {
        bf16x8 bv = *(const bf16x8*)&Vt[(nt*16 + l16)*72 + kc*32 + quad*8];
        o[nt] = __builtin_amdgcn_mfma_f32_16x16x32_bf16(ap, bv, o[nt], 0, 0, 0);
      }
    }
  }

  float l[4];
  #pragma unroll
  for (int r = 0; r < 4; ++r) {
    float rs = pl[r];
    #pragma unroll
    for (int off = 1; off < 16; off <<= 1) rs += __shfl_xor(rs, off);
    l[r] = rs;
  }

  #pragma unroll
  for (int nt = 0; nt < 4; ++nt)
    #pragma unroll
    for (int r = 0; r < 4; ++r) {
      int n = qt*64 + w*16 + quad*4 + r;
      int dcol = nt*16 + l16;
      ob[((size_t)(b*NN + n)*HEADS + h)*DH + dcol] = __float2bfloat16(o[nt][r] / l[r]);
    }
}

// ---------------------------------------------------------------------------
// Fused weight transpose: 5 weights f32 (RxC) -> bf16 (CxR), one dispatch.
// gam: optional per-input-row gamma fold. perm=1 (wff1): interleave a/g cols.
// ---------------------------------------------------------------------------
struct TD { const float* src; bf16* dst; const float* gam; int R, C, base, perm; };
struct TDs5 { TD d[5]; };

__global__ __launch_bounds__(256) void wtrans_kernel(TDs5 a)
{
  const int blk = blockIdx.x;
  int di = 0;
  #pragma unroll
  for (int k = 1; k < 5; ++k) if (blk >= a.d[k].base) di = k;
  const TD d = a.d[di];
  const int local = blk - d.base;
  const int tilesX = d.C >> 5;
  const int by = local / tilesX, bx = local - by*tilesX;
  __shared__ float t[32][33];
  const int tx = threadIdx.x & 31, ty = threadIdx.x >> 5;
  const int c0 = bx*32, r0 = by*32;
  #pragma unroll
  for (int i = 0; i < 4; ++i)
    t[ty + i*8][tx] = d.src[(size_t)(r0 + ty + i*8)*d.C + c0 + tx];
  __syncthreads();
  const float gv = d.gam ? d.gam[r0 + tx] : 1.f;
  const int half = d.C >> 1;
  #pragma unroll
  for (int i = 0; i < 4; ++i) {
    int c = c0 + ty + i*8;
    int rout = d.perm ? ((c < half) ? 2*c : 2*(c - half) + 1) : c;
    d.dst[(size_t)rout*d.R + r0 + tx] = __float2bfloat16(gv * t[tx][ty + i*8]);
  }
}

// ---------------------------------------------------------------------------
// Fold vectors: vq[c]=row-sum of w~qT; vff1[c]=row-sum of w~ff1T (both have
// gamma folded, c already in GEMM col space); bff1[c]=sum_j beta_j wff1[j,c]
// from f32 source, stored at interleaved position.
// ---------------------------------------------------------------------------
__global__ __launch_bounds__(256) void foldv_kernel(
    const bf16* __restrict__ wqT, const bf16* __restrict__ wff1T,
    const float* __restrict__ fbeta, const float* __restrict__ wff1src,
    float* __restrict__ vqv, float* __restrict__ vff1v, float* __restrict__ bff1v)
{
  const int blk = blockIdx.x;
  if (blk < 1216) {
    int gr = blk*4 + (threadIdx.x >> 6);
    int lane = threadIdx.x & 63;
    const bf16* src; float* dst;
    if (gr < 768) { src = wqT + (size_t)gr*768; dst = vqv + gr; }
    else          { src = wff1T + (size_t)(gr-768)*768; dst = vff1v + (gr-768); }
    float s = 0.f;
    #pragma unroll
    for (int k2 = 0; k2 < 12; ++k2) s += __bfloat162float(src[lane + k2*64]);
    #pragma unroll
    for (int off = 1; off < 64; off <<= 1) s += __shfl_xor(s, off);
    if (lane == 0) *dst = s;
  } else {
    int c = (blk - 1216)*256 + threadIdx.x;      // 0..4095
    float s = 0.f;
    for (int j = 0; j < 768; ++j) s += fbeta[j] * wff1src[(size_t)j*4096 + c];
    int rout = (c < 2048) ? 2*c : 2*(c - 2048) + 1;
    bff1v[rout] = s;
  }
}

// ---------------------------------------------------------------------------
extern "C" void kernel_launch(void* const* d_in, const int* in_sizes, int n_in,
                              void* d_out, int out_size, void* d_ws, size_t ws_size,
                              hipStream_t stream)
{
  const float* x_in       = (const float*)d_in[0];
  const float* attn_gamma = (const float*)d_in[1];
  const float* wq         = (const float*)d_in[2];
  const float* wkv        = (const float*)d_in[3];
  const float* q_scale    = (const float*)d_in[4];
  const float* k_scale    = (const float*)d_in[5];
  const float* wo         = (const float*)d_in[6];
  const float* ff_gamma   = (const float*)d_in[7];
  const float* ff_beta    = (const float*)d_in[8];
  const float* wff1       = (const float*)d_in[9];
  const float* wff2       = (const float*)d_in[10];
  float* outp = (float*)d_out;
  char* ws = (char*)d_ws;

  const size_t E = (size_t)ROWS * DIM;      // 3,145,728 elems
  // Arena layout (bytes):
  float*  xw32  = (float*)ws;                    // [0, 12.58M) f32 residual
  bf16*   xw16  = (bf16*)(ws + 12582912);        // bf16 shadow of x
  bf16*   S_h   = (bf16*)(ws + 18874368);        // attention output
  float2* musig = (float2*)(ws + 25165824);      // 4096 x {mu,rstd}
  float*  vqv   = (float*)(ws + 25198592);       // 768
  float*  vff1v = (float*)(ws + 25201664);       // 4096 (interleaved)
  float*  bff1v = (float*)(ws + 25218048);       // 4096 (interleaved)
  char*   BIGb  = ws + 25296896;                 // 37.75M scratch
  bf16*   WT    = (bf16*)(ws + 63045632);        // transposed weights 14.16M
  bf16*  qbuf  = (bf16*)BIGb;                    // E elems
  bf16*  kbuf  = qbuf + E;                       // E
  bf16*  qhb   = qbuf + 2*E;                     // E
  bf16*  khb   = qbuf + 3*E;                     // E
  bf16*  vtb   = qbuf + 4*E;                     // E
  bf16*  glbuf = (bf16*)BIGb;                    // ROWS*FFI (q..vt dead then)
  float* wP    = (float*)BIGb;                   // wo partials 2E f32
  float* fP    = (float*)(BIGb + 16777216);      // ff2 partials 2E f32 (tail
                                                 //   spills into dead wqT..woT)
  bf16*  wqT   = WT;                             // [768][768]   gamma-folded
  bf16*  wkvT  = WT + 589824;                    // [1536][768]  (contig after wqT)
  bf16*  woT   = WT + 1769472;                   // [768][768]
  bf16*  wff1T = WT + 2359296;                   // [4096][768]  gamma-folded, interleaved
  bf16*  wff2T = WT + 5505024;                   // [768][2048]

  stats_kernel<<<ROWS, 256, 0, stream>>>(x_in, xw16, musig);

  for (int i = 0; i < NDEPTH; ++i) {
    const float* xsrc = (i == 0) ? x_in : xw32;

    TDs5 td;
    td.d[0] = { wq   + (size_t)i*589824,  wqT,   attn_gamma + i*DIM, 768,  768,    0, 0 };
    td.d[1] = { wkv  + (size_t)i*1179648, wkvT,  nullptr,            768, 1536,  576, 0 };
    td.d[2] = { wo   + (size_t)i*589824,  woT,   nullptr,            768,  768, 1728, 0 };
    td.d[3] = { wff1 + (size_t)i*3145728, wff1T, ff_gamma + i*DIM,   768, 4096, 2304, 1 };
    td.d[4] = { wff2 + (size_t)i*1572864, wff2T, nullptr,           2048,  768, 5376, 0 };
    wtrans_kernel<<<6912, 256, 0, stream>>>(td);
    foldv_kernel<<<1232, 256, 0, stream>>>(wqT, wff1T, ff_beta + i*DIM,
                                           wff1 + (size_t)i*3145728, vqv, vff1v, bff1v);

    // q,k,v in ONE GEMM over A=xw16; q gets LN-fold (-mu*vq; rstd cancels in rope)
    qkv_kernel<<<dim3(18,32), 256, 0, stream>>>(xw16, wqT, qbuf, kbuf, vtb, musig, vqv);
    rope_kernel<<<ROWS, 384, 0, stream>>>(qbuf, kbuf, q_scale + i*DH, k_scale + i*DH, qhb, khb);
    attn_kernel<<<dim3(16,48), 256, 0, stream>>>(qhb, khb, vtb,
                                                 q_scale + i*DH, k_scale + i*DH, S_h);
    // x1 = x + o @ wo (split-K=2) ; reduce + residual + stats(x1)
    gemm_splitk_kernel<64,384,768><<<dim3(12,32,2), 256, 0, stream>>>(S_h, woT, wP, ROWS, DIM);
    redln_kernel<<<ROWS, 256, 0, stream>>>(wP, wP + E, xsrc, xw32, xw16, nullptr, musig);
    // FF1 with LN-fold + SwiGLU fused
    ff1_kernel<<<dim3(32,32), 256, 0, stream>>>(xw16, wff1T, glbuf, musig, vff1v, bff1v,
                                                ROWS, 2*FFI);
    // x2 = x1 + gl @ wff2 (split-K=2) ; reduce + residual + stats(x2)
    gemm_splitk_kernel<64,1024,2048><<<dim3(12,32,2), 256, 0, stream>>>(glbuf, wff2T, fP, ROWS, DIM);
    if (i < NDEPTH-1)
      redln_kernel<<<ROWS, 256, 0, stream>>>(fP, fP + E, xw32, xw32, xw16, nullptr, musig);
    else
      redln_kernel<<<ROWS, 256, 0, stream>>>(fP, fP + E, xw32, nullptr, nullptr, outp, musig);
  }
}